// Round 1
// baseline (313.232 us; speedup 1.0000x reference)
//
#include <hip/hip_runtime.h>

#define NBINS 20

// Kernel 1: grid-stride histogram. Per-wave LDS copies (4/block) to cut
// atomic contention. cnt and sum_t are small ints -> packed into one u32
// (cnt in lo16, sum_t in hi16): 2 LDS atomics per element instead of 3.
// Each block writes its 60 partial stats to ws[block*64 + col]:
//   col 0..19 = cnt, 20..39 = sum_p, 40..59 = sum_t.
__global__ __launch_bounds__(256) void ace_hist(const float* __restrict__ preds,
                                                const int* __restrict__ tgt,
                                                float* __restrict__ ws, int n) {
    __shared__ unsigned int hct[4][NBINS]; // packed: cnt | (sum_t << 16)
    __shared__ float hsp[4][NBINS];        // sum of preds
    const int t = threadIdx.x;
    const int wave = t >> 6;

    for (int i = t; i < 4 * NBINS; i += blockDim.x) {
        (&hct[0][0])[i] = 0u;
        (&hsp[0][0])[i] = 0.0f;
    }
    __syncthreads();

#define PROC(pp, tt) do {                                              \
        float _p = (pp);                                               \
        if (_p >= 0.0f && _p < 1.0f) {                                 \
            int _b = (int)(_p * 20.0f);                                \
            _b = _b > (NBINS - 1) ? (NBINS - 1) : _b;                  \
            atomicAdd(&hct[wave][_b], 1u + ((unsigned)(tt) << 16));    \
            atomicAdd(&hsp[wave][_b], _p);                             \
        }                                                              \
    } while (0)

    const int n4 = n >> 2;
    const float4* p4 = (const float4*)preds;
    const int4*   t4 = (const int4*)tgt;
    const int stride = gridDim.x * blockDim.x;
    for (int i = blockIdx.x * blockDim.x + t; i < n4; i += stride) {
        float4 p = p4[i];
        int4   tv = t4[i];
        PROC(p.x, tv.x);
        PROC(p.y, tv.y);
        PROC(p.z, tv.z);
        PROC(p.w, tv.w);
    }
    // tail (n not divisible by 4)
    if (blockIdx.x == 0) {
        for (int i = (n4 << 2) + t; i < n; i += blockDim.x) {
            float p = preds[i];
            int   tv = tgt[i];
            PROC(p, tv);
        }
    }
#undef PROC
    __syncthreads();

    if (t < 64) {
        float v = 0.0f;
        if (t < NBINS) {
            unsigned c = (hct[0][t] & 0xFFFFu) + (hct[1][t] & 0xFFFFu) +
                         (hct[2][t] & 0xFFFFu) + (hct[3][t] & 0xFFFFu);
            v = (float)c;
        } else if (t < 2 * NBINS) {
            int b = t - NBINS;
            v = hsp[0][b] + hsp[1][b] + hsp[2][b] + hsp[3][b];
        } else if (t < 3 * NBINS) {
            int b = t - 2 * NBINS;
            v = (float)((hct[0][b] >> 16) + (hct[1][b] >> 16) +
                        (hct[2][b] >> 16) + (hct[3][b] >> 16));
        }
        ws[(size_t)blockIdx.x * 64 + t] = v;
    }
}

// Kernel 2: reduce nblk partial rows of 64 floats, then the 20-bin epilogue.
__global__ __launch_bounds__(256) void ace_reduce(const float* __restrict__ ws,
                                                  float* __restrict__ out, int nblk) {
    __shared__ float part[4][64];
    const int t = threadIdx.x;
    const int col = t & 63;
    const int g = t >> 6;
    float s = 0.0f;
    for (int r = g; r < nblk; r += 4)
        s += ws[(size_t)r * 64 + col];
    part[g][col] = s;
    __syncthreads();
    if (t < 64) {
        float fin = part[0][t] + part[1][t] + part[2][t] + part[3][t];
        part[0][t] = fin;
    }
    __syncthreads();
    if (t < 64) {
        float term = 0.0f;
        if (t < NBINS) {
            float cnt = part[0][t];
            float sp  = part[0][NBINS + t];
            float st  = part[0][2 * NBINS + t];
            if (cnt > 0.0f) term = fabsf(sp - st) / cnt;  // |e - o| = |sp-st|/cnt
        }
        for (int off = 32; off; off >>= 1)
            term += __shfl_down(term, off);
        if (t == 0) out[0] = term / (float)NBINS;
    }
}

extern "C" void kernel_launch(void* const* d_in, const int* in_sizes, int n_in,
                              void* d_out, int out_size, void* d_ws, size_t ws_size,
                              hipStream_t stream) {
    const float* preds = (const float*)d_in[0];
    const int*   tgt   = (const int*)d_in[1];
    float* out = (float*)d_out;
    float* ws  = (float*)d_ws;
    const int n = in_sizes[0];

    int nblk = 2048;
    if ((size_t)nblk * 64 * sizeof(float) > ws_size) {
        nblk = (int)(ws_size / (64 * sizeof(float)));
        if (nblk < 1) nblk = 1;
    }

    ace_hist<<<nblk, 256, 0, stream>>>(preds, tgt, ws, n);
    ace_reduce<<<1, 256, 0, stream>>>(ws, out, nblk);
}

// Round 2
// 51.275 us; speedup vs baseline: 6.1089x; 6.1089x over previous
//
#include <hip/hip_runtime.h>

#define NBINS 20
#define NSUB  8   // sub-histograms per wave (lane & 7) to cut same-address atomic serialization

// Kernel 1: grid-stride histogram. One 64-bit LDS atomic per element:
//   bits [0:28)  = sum of frac = p*20 - bin, quantized to 1/65536
//   bits [28:46) = count
//   bits [46:64) = sum of targets
// sum_p is reconstructed as (bin*cnt + fracsum/65536) / 20.
// 4 waves x 8 subs = 32 histogram copies -> ~0.4 avg same-address collisions.
// Each block writes 60 partials to ws[block*64 + col]:
//   col 0..19 = cnt, 20..39 = sum_p, 40..59 = sum_t.
__global__ __launch_bounds__(256) void ace_hist(const float* __restrict__ preds,
                                                const int* __restrict__ tgt,
                                                float* __restrict__ ws, int n) {
    __shared__ unsigned long long h[4][NSUB][NBINS];
    const int t = threadIdx.x;
    const int wave = t >> 6;
    const int sub  = t & (NSUB - 1);
    unsigned long long* hw = h[wave][sub];

    for (int i = t; i < 4 * NSUB * NBINS; i += 256)
        (&h[0][0][0])[i] = 0ull;
    __syncthreads();

#define PROC(pp, tt) do {                                                    \
        float _p = (pp);                                                     \
        if (_p >= 0.0f && _p < 1.0f) {                                       \
            float _pf = _p * 20.0f;                                          \
            int _b = (int)_pf;                                               \
            _b = _b > (NBINS - 1) ? (NBINS - 1) : _b;                        \
            float _fr = _pf - (float)_b;                                     \
            unsigned _q = (unsigned)(_fr * 65536.0f);                        \
            _q = _q > 65535u ? 65535u : _q;                                  \
            unsigned long long _add = (unsigned long long)_q                 \
                                    + (1ULL << 28)                           \
                                    + ((unsigned long long)(unsigned)(tt) << 46); \
            atomicAdd(&hw[_b], _add);                                        \
        }                                                                    \
    } while (0)

    const int n4 = n >> 2;
    const float4* p4 = (const float4*)preds;
    const int4*   t4 = (const int4*)tgt;
    const int stride = gridDim.x * blockDim.x;
    for (int i = blockIdx.x * blockDim.x + t; i < n4; i += stride) {
        float4 p  = p4[i];
        int4   tv = t4[i];
        PROC(p.x, tv.x);
        PROC(p.y, tv.y);
        PROC(p.z, tv.z);
        PROC(p.w, tv.w);
    }
    if (blockIdx.x == 0) {  // tail if n % 4 != 0
        for (int i = (n4 << 2) + t; i < n; i += blockDim.x)
            PROC(preds[i], tgt[i]);
    }
#undef PROC
    __syncthreads();

    if (t < NBINS) {
        float cnt = 0.0f, fr = 0.0f, st = 0.0f;
        for (int w = 0; w < 4; ++w)
            for (int s = 0; s < NSUB; ++s) {
                unsigned long long v = h[w][s][t];
                fr  += (float)(unsigned)(v & 0xFFFFFFFull);
                cnt += (float)(unsigned)((v >> 28) & 0x3FFFFull);
                st  += (float)(unsigned)(v >> 46);
            }
        float sp = (cnt * (float)t + fr * (1.0f / 65536.0f)) * 0.05f;
        size_t base = (size_t)blockIdx.x * 64;
        ws[base + t]             = cnt;
        ws[base + NBINS + t]     = sp;
        ws[base + 2 * NBINS + t] = st;
    }
}

// Kernel 2: one block, 1024 threads (16 row-groups x 64 cols), 8-way unrolled
// independent accumulators to hide load latency, then the 20-bin epilogue.
__global__ __launch_bounds__(1024) void ace_reduce(const float* __restrict__ ws,
                                                   float* __restrict__ out, int nblk) {
    __shared__ float part[16][64];
    const int t = threadIdx.x;
    const int col = t & 63;
    const int g = t >> 6;  // 0..15
    float s = 0.0f;
    if (col < 3 * NBINS) {
        float a0 = 0, a1 = 0, a2 = 0, a3 = 0, a4 = 0, a5 = 0, a6 = 0, a7 = 0;
        int r = g;
        for (; r + 112 < nblk; r += 128) {
            a0 += ws[(size_t)(r      ) * 64 + col];
            a1 += ws[(size_t)(r +  16) * 64 + col];
            a2 += ws[(size_t)(r +  32) * 64 + col];
            a3 += ws[(size_t)(r +  48) * 64 + col];
            a4 += ws[(size_t)(r +  64) * 64 + col];
            a5 += ws[(size_t)(r +  80) * 64 + col];
            a6 += ws[(size_t)(r +  96) * 64 + col];
            a7 += ws[(size_t)(r + 112) * 64 + col];
        }
        for (; r < nblk; r += 16)
            a0 += ws[(size_t)r * 64 + col];
        s = ((a0 + a1) + (a2 + a3)) + ((a4 + a5) + (a6 + a7));
    }
    part[g][col] = s;
    __syncthreads();
    if (t < 64) {
        float fin = 0.0f;
        for (int i = 0; i < 16; ++i) fin += part[i][t];
        part[0][t] = fin;
    }
    __syncthreads();
    if (t < 64) {
        float term = 0.0f;
        if (t < NBINS) {
            float cnt = part[0][t];
            float sp  = part[0][NBINS + t];
            float st  = part[0][2 * NBINS + t];
            if (cnt > 0.0f) term = fabsf(sp - st) / cnt;  // |e-o| = |sp-st|/cnt
        }
        for (int off = 32; off; off >>= 1)
            term += __shfl_down(term, off);
        if (t == 0) out[0] = term / (float)NBINS;
    }
}

extern "C" void kernel_launch(void* const* d_in, const int* in_sizes, int n_in,
                              void* d_out, int out_size, void* d_ws, size_t ws_size,
                              hipStream_t stream) {
    const float* preds = (const float*)d_in[0];
    const int*   tgt   = (const int*)d_in[1];
    float* out = (float*)d_out;
    float* ws  = (float*)d_ws;
    const int n = in_sizes[0];

    int nblk = 2048;
    if ((size_t)nblk * 64 * sizeof(float) > ws_size) {
        nblk = (int)(ws_size / (64 * sizeof(float)));
        if (nblk < 1) nblk = 1;
    }

    ace_hist<<<nblk, 256, 0, stream>>>(preds, tgt, ws, n);
    ace_reduce<<<1, 1024, 0, stream>>>(ws, out, nblk);
}